// Round 1
// baseline (1231.771 us; speedup 1.0000x reference)
//
#include <hip/hip_runtime.h>
#include <hip/hip_bf16.h>

// GraphAutoencoder: 3x GraphConv (DGL norm='both') on fixed graph.
// N=50000 nodes, E=600000 edges, widths 128 -> 64 -> 32 -> 128.
//
// Algebraic restructure: agg(X) @ W == agg(X @ W) (segment_sum is linear,
// W is per-row). So aggregate at the NARROW width each layer:
//   L1: t1 = rs_out .* (X @ W1)        [50000,64]; agg1 = scatter(t1);  h1 = relu(rs_in.*agg1 + b1)
//   L2: t2 = rs_out .* (h1 @ W2)       [50000,32]; aggz = scatter(t2);  z  = rs_in.*aggz + b2   -> d_out[0:1.6M]
//   L3: agg3 = scatter(rs_out .* z)    [50000,32]; recon = (rs_in.*agg3) @ W3 + b3              -> d_out[1.6M:8M]

#define DEV_INLINE __device__ __forceinline__

static DEV_INLINE void atomic_add_f32(float* p, float v) {
    // hardware global_atomic_add_f32 (device memory is coarse-grained)
    unsafeAtomicAdd(p, v);
}

__global__ void k_degrees(const int* __restrict__ src, const int* __restrict__ dst,
                          float* __restrict__ deg_out, float* __restrict__ deg_in, int E) {
    int i = blockIdx.x * blockDim.x + threadIdx.x;
    if (i < E) {
        atomic_add_f32(&deg_out[src[i]], 1.0f);
        atomic_add_f32(&deg_in[dst[i]], 1.0f);
    }
}

__global__ void k_rsqrt_deg(float* __restrict__ deg_out, float* __restrict__ deg_in, int n) {
    int i = blockIdx.x * blockDim.x + threadIdx.x;
    if (i < n) {
        deg_out[i] = rsqrtf(fmaxf(deg_out[i], 1.0f));
        deg_in[i]  = rsqrtf(fmaxf(deg_in[i], 1.0f));
    }
}

// Y[r,c] = rowscale[r] * (X[r,:] @ W)[c]  (+ bias[c] if bias != nullptr)
template <int IN_F, int OUT_F, int ROWS>
__global__ __launch_bounds__(256) void k_gemm_rowscale(
    const float* __restrict__ X, const float* __restrict__ W,
    const float* __restrict__ rowscale, const float* __restrict__ bias,
    float* __restrict__ Y, int n)
{
    __shared__ float sW[IN_F * OUT_F];
    __shared__ float sX[ROWS * IN_F];
    const int tid = threadIdx.x;
    const int row0 = blockIdx.x * ROWS;

    for (int i = tid; i < IN_F * OUT_F; i += 256) sW[i] = W[i];
    for (int i = tid; i < ROWS * IN_F; i += 256) {
        long g = (long)row0 * IN_F + i;
        sX[i] = (g < (long)n * IN_F) ? X[g] : 0.0f;
    }
    __syncthreads();

    for (int o = tid; o < ROWS * OUT_F; o += 256) {
        const int r = o / OUT_F;
        const int c = o % OUT_F;
        float acc = 0.0f;
#pragma unroll
        for (int k = 0; k < IN_F; ++k) acc += sX[r * IN_F + k] * sW[k * OUT_F + c];
        const int gr = row0 + r;
        if (gr < n) {
            float v = acc * rowscale[gr];
            if (bias) v += bias[c];
            Y[(long)gr * OUT_F + c] = v;
        }
    }
}

// A[dst[e], :] += X[src[e], :] (* srcscale[src[e]] if given), vectorized float4.
template <int F>
__global__ __launch_bounds__(256) void k_scatter(
    const int* __restrict__ src, const int* __restrict__ dst,
    const float* __restrict__ X, const float* __restrict__ srcscale,
    float* __restrict__ A, int E)
{
    constexpr unsigned PE = F / 4;  // float4 chunks per edge
    unsigned idx = blockIdx.x * blockDim.x + threadIdx.x;
    if (idx >= (unsigned)E * PE) return;
    const int e  = idx / PE;
    const int f4 = (idx % PE) * 4;
    const int s = src[e];
    const int d = dst[e];
    float4 v = *(const float4*)(X + (long)s * F + f4);
    if (srcscale) {
        const float sc = srcscale[s];
        v.x *= sc; v.y *= sc; v.z *= sc; v.w *= sc;
    }
    float* a = A + (long)d * F + f4;
    atomic_add_f32(a + 0, v.x);
    atomic_add_f32(a + 1, v.y);
    atomic_add_f32(a + 2, v.z);
    atomic_add_f32(a + 3, v.w);
}

// O[r,c] = op(rs_in[r]*A[r,c] + bias[c]); op = relu or identity. O may alias A.
template <int F, bool RELU>
__global__ __launch_bounds__(256) void k_epilogue(
    const float* __restrict__ A, const float* __restrict__ rs_in,
    const float* __restrict__ bias, float* __restrict__ O, int n)
{
    long idx = (long)blockIdx.x * blockDim.x + threadIdx.x;
    if (idx < (long)n * F) {
        const int r = (int)(idx / F);
        const int c = (int)(idx % F);
        float v = A[idx] * rs_in[r] + bias[c];
        if (RELU) v = fmaxf(v, 0.0f);
        O[idx] = v;
    }
}

extern "C" void kernel_launch(void* const* d_in, const int* in_sizes, int n_in,
                              void* d_out, int out_size, void* d_ws, size_t ws_size,
                              hipStream_t stream) {
    const float* feat = (const float*)d_in[0];   // [N,128]
    const int*   src  = (const int*)d_in[1];     // [E]
    const int*   dst  = (const int*)d_in[2];     // [E]
    const float* W1   = (const float*)d_in[3];   // [128,64]
    const float* b1   = (const float*)d_in[4];   // [64]
    const float* W2   = (const float*)d_in[5];   // [64,32]
    const float* b2   = (const float*)d_in[6];   // [32]
    const float* W3   = (const float*)d_in[7];   // [32,128]
    const float* b3   = (const float*)d_in[8];   // [128]

    const int E = in_sizes[1];
    const int N = in_sizes[0] / 128;             // 50000

    // Workspace layout (floats). Zeroed region first (one memset).
    float* ws      = (float*)d_ws;
    float* rs_out  = ws;                         // [N]   deg_out -> rsqrt
    float* rs_in   = rs_out + N;                 // [N]   deg_in  -> rsqrt
    float* agg1    = rs_in + N;                  // [N,64] (h1 in-place after epilogue)
    float* aggz    = agg1 + (long)N * 64;        // [N,32]
    float* agg3    = aggz + (long)N * 32;        // [N,32]
    const long zero_floats = 2L * N + (long)N * (64 + 32 + 32);
    float* t1      = agg3 + (long)N * 32;        // [N,64]
    float* t2      = t1 + (long)N * 64;          // [N,32]

    float* z_out   = (float*)d_out;              // [N,32]
    float* recon   = z_out + (long)N * 32;       // [N,128]

    hipMemsetAsync(ws, 0, zero_floats * sizeof(float), stream);

    const int B = 256;
    k_degrees<<<(E + B - 1) / B, B, 0, stream>>>(src, dst, rs_out, rs_in, E);
    k_rsqrt_deg<<<(N + B - 1) / B, B, 0, stream>>>(rs_out, rs_in, N);

    // Layer 1: 128 -> 64
    k_gemm_rowscale<128, 64, 16><<<(N + 15) / 16, B, 0, stream>>>(feat, W1, rs_out, nullptr, t1, N);
    k_scatter<64><<<((long)E * 16 + B - 1) / B, B, 0, stream>>>(src, dst, t1, nullptr, agg1, E);
    k_epilogue<64, true><<<((long)N * 64 + B - 1) / B, B, 0, stream>>>(agg1, rs_in, b1, agg1, N);

    // Layer 2: 64 -> 32, z to d_out
    k_gemm_rowscale<64, 32, 16><<<(N + 15) / 16, B, 0, stream>>>(agg1, W2, rs_out, nullptr, t2, N);
    k_scatter<32><<<((long)E * 8 + B - 1) / B, B, 0, stream>>>(src, dst, t2, nullptr, aggz, E);
    k_epilogue<32, false><<<((long)N * 32 + B - 1) / B, B, 0, stream>>>(aggz, rs_in, b2, z_out, N);

    // Layer 3: aggregate z (width 32) then expand 32 -> 128
    k_scatter<32><<<((long)E * 8 + B - 1) / B, B, 0, stream>>>(src, dst, z_out, rs_out, agg3, E);
    k_gemm_rowscale<32, 128, 16><<<(N + 15) / 16, B, 0, stream>>>(agg3, W3, rs_in, b3, recon, N);
}

// Round 2
// 339.579 us; speedup vs baseline: 3.6273x; 3.6273x over previous
//
#include <hip/hip_runtime.h>
#include <hip/hip_bf16.h>

// GraphAutoencoder: 3x GraphConv (DGL norm='both') on fixed graph.
// N=50000 nodes, E=600000 edges, widths 128 -> 64 -> 32 -> 128.
//
// R1 finding: scatter-atomic aggregation was atomic-RMW bound (485us for F=64,
// WRITE_SIZE showed 64B writeback per 16B atomic chunk). R2: build dst-sorted
// CSR once per call, aggregate by GATHER (no atomics), fuse epilogue.
//
// Algebra: agg(X) @ W == agg(X @ W)  -> aggregate at the narrow width:
//   L1: t1 = rs_out .* (X @ W1);  h1 = relu(rs_in .* gather(t1) + b1)
//   L2: t2 = rs_out .* (h1 @ W2); z  = rs_in .* gather(t2) + b2       -> d_out[0:1.6M]
//   L3: agg3 = rs_in .* gather(rs_out[src] .* z); recon = agg3 @ W3 + b3 -> d_out[1.6M:8M]

// ---------- degree histogram ----------
__global__ void k_hist(const int* __restrict__ src, const int* __restrict__ dst,
                       int* __restrict__ cnt_out, int* __restrict__ cnt_in, int E) {
    int i = blockIdx.x * blockDim.x + threadIdx.x;
    if (i < E) {
        atomicAdd(&cnt_out[src[i]], 1);
        atomicAdd(&cnt_in[dst[i]], 1);
    }
}

__global__ void k_rsqrt_deg(const int* __restrict__ cnt_out, const int* __restrict__ cnt_in,
                            float* __restrict__ rs_out, float* __restrict__ rs_in, int n) {
    int i = blockIdx.x * blockDim.x + threadIdx.x;
    if (i < n) {
        rs_out[i] = rsqrtf(fmaxf((float)cnt_out[i], 1.0f));
        rs_in[i]  = rsqrtf(fmaxf((float)cnt_in[i], 1.0f));
    }
}

// ---------- prefix scan of cnt_in -> row_ptr (size n+1) + cursor (excl scan) ----------
__global__ void k_scan1(const int* __restrict__ cnt, int* __restrict__ partial,
                        int* __restrict__ blocksum, int n) {
    __shared__ int tmp[256];
    const int tid = threadIdx.x;
    const int i = blockIdx.x * 256 + tid;
    int v = (i < n) ? cnt[i] : 0;
    tmp[tid] = v; __syncthreads();
    for (int off = 1; off < 256; off <<= 1) {
        int t = (tid >= off) ? tmp[tid - off] : 0;
        __syncthreads(); tmp[tid] += t; __syncthreads();
    }
    if (i < n) partial[i] = tmp[tid];                 // inclusive within block
    if (tid == 255) blocksum[blockIdx.x] = tmp[255];
}

__global__ void k_scan2(int* __restrict__ blocksum, int nb) {  // single block, nb<=256
    __shared__ int tmp[256];
    const int tid = threadIdx.x;
    int v = (tid < nb) ? blocksum[tid] : 0;
    tmp[tid] = v; __syncthreads();
    for (int off = 1; off < 256; off <<= 1) {
        int t = (tid >= off) ? tmp[tid - off] : 0;
        __syncthreads(); tmp[tid] += t; __syncthreads();
    }
    if (tid < nb) blocksum[tid] = tmp[tid];           // inclusive scan of block sums
}

__global__ void k_scan3(const int* __restrict__ cnt, const int* __restrict__ partial,
                        const int* __restrict__ blocksum,
                        int* __restrict__ row_ptr, int* __restrict__ cursor, int n) {
    const int i = blockIdx.x * 256 + threadIdx.x;
    if (i < n) {
        const int base = (blockIdx.x > 0) ? blocksum[blockIdx.x - 1] : 0;
        const int incl = partial[i] + base;
        row_ptr[i + 1] = incl;
        cursor[i] = incl - cnt[i];                    // exclusive
        if (i == 0) row_ptr[0] = 0;
    }
}

__global__ void k_fill(const int* __restrict__ src, const int* __restrict__ dst,
                       int* __restrict__ cursor, int* __restrict__ csr_src, int E) {
    int e = blockIdx.x * blockDim.x + threadIdx.x;
    if (e < E) {
        int pos = atomicAdd(&cursor[dst[e]], 1);
        csr_src[pos] = src[e];
    }
}

// ---------- dense GEMM with optional row scale / bias ----------
// Y[r,c] = (rowscale?rowscale[r]:1) * (X[r,:] @ W)[c] (+ bias[c] if bias)
template <int IN_F, int OUT_F, int ROWS>
__global__ __launch_bounds__(256) void k_gemm_rowscale(
    const float* __restrict__ X, const float* __restrict__ W,
    const float* __restrict__ rowscale, const float* __restrict__ bias,
    float* __restrict__ Y, int n)
{
    __shared__ float sW[IN_F * OUT_F];
    __shared__ float sX[ROWS * IN_F];
    const int tid = threadIdx.x;
    const int row0 = blockIdx.x * ROWS;

    for (int i = tid; i < IN_F * OUT_F; i += 256) sW[i] = W[i];
    for (int i = tid; i < ROWS * IN_F; i += 256) {
        long g = (long)row0 * IN_F + i;
        sX[i] = (g < (long)n * IN_F) ? X[g] : 0.0f;
    }
    __syncthreads();

    for (int o = tid; o < ROWS * OUT_F; o += 256) {
        const int r = o / OUT_F;
        const int c = o % OUT_F;
        float acc = 0.0f;
#pragma unroll
        for (int k = 0; k < IN_F; ++k) acc += sX[r * IN_F + k] * sW[k * OUT_F + c];
        const int gr = row0 + r;
        if (gr < n) {
            float v = acc;
            if (rowscale) v *= rowscale[gr];
            if (bias) v += bias[c];
            Y[(long)gr * OUT_F + c] = v;
        }
    }
}

// ---------- CSR gather-aggregate, fused epilogue ----------
// O[d,c] = op( rs_in[d] * sum_{j in [row_ptr[d],row_ptr[d+1])} X[csr_src[j],c]
//              * (SRCSCALE ? srcscale[csr_src[j]] : 1)  + (HAS_BIAS ? bias[c] : 0) )
template <int F, bool RELU, bool SRCSCALE, bool HAS_BIAS>
__global__ __launch_bounds__(256) void k_gather(
    const int* __restrict__ row_ptr, const int* __restrict__ csr_src,
    const float* __restrict__ X, const float* __restrict__ srcscale,
    const float* __restrict__ rs_in, const float* __restrict__ bias,
    float* __restrict__ O, int N)
{
    constexpr int NODES = 256 / F;
    const int node = blockIdx.x * NODES + threadIdx.x / F;
    const int c = threadIdx.x % F;
    if (node >= N) return;

    const int beg = row_ptr[node];
    const int end = row_ptr[node + 1];
    float acc0 = 0.0f, acc1 = 0.0f;
    int j = beg;
    for (; j + 1 < end; j += 2) {       // 2-way unroll: two loads in flight
        const int s0 = csr_src[j];
        const int s1 = csr_src[j + 1];
        float v0 = X[(long)s0 * F + c];
        float v1 = X[(long)s1 * F + c];
        if (SRCSCALE) { v0 *= srcscale[s0]; v1 *= srcscale[s1]; }
        acc0 += v0; acc1 += v1;
    }
    if (j < end) {
        const int s = csr_src[j];
        float v = X[(long)s * F + c];
        if (SRCSCALE) v *= srcscale[s];
        acc0 += v;
    }
    float out = (acc0 + acc1) * rs_in[node];
    if (HAS_BIAS) out += bias[c];
    if (RELU) out = fmaxf(out, 0.0f);
    O[(long)node * F + c] = out;
}

extern "C" void kernel_launch(void* const* d_in, const int* in_sizes, int n_in,
                              void* d_out, int out_size, void* d_ws, size_t ws_size,
                              hipStream_t stream) {
    const float* feat = (const float*)d_in[0];   // [N,128]
    const int*   src  = (const int*)d_in[1];     // [E]
    const int*   dst  = (const int*)d_in[2];     // [E]
    const float* W1   = (const float*)d_in[3];   // [128,64]
    const float* b1   = (const float*)d_in[4];   // [64]
    const float* W2   = (const float*)d_in[5];   // [64,32]
    const float* b2   = (const float*)d_in[6];   // [32]
    const float* W3   = (const float*)d_in[7];   // [32,128]
    const float* b3   = (const float*)d_in[8];   // [128]

    const int E = in_sizes[1];
    const int N = in_sizes[0] / 128;             // 50000

    // ---- workspace layout ----
    int* cnt_out = (int*)d_ws;                   // [N]
    int* cnt_in  = cnt_out + N;                  // [N]
    int* row_ptr = cnt_in + N;                   // [N+1]
    int* cursor  = row_ptr + N + 1;              // [N]
    int* scan_p  = cursor + N;                   // [N]   (block-local inclusive scans)
    int* blocksum= scan_p + N;                   // [256]
    int* csr_src = blocksum + 256;               // [E]
    float* rs_out = (float*)(csr_src + E);       // [N]
    float* rs_in  = rs_out + N;                  // [N]
    float* t1     = rs_in + N;                   // [N,64]
    float* h1     = t1 + (long)N * 64;           // [N,64]
    float* t2     = h1 + (long)N * 64;           // [N,32]
    float* agg3   = t2 + (long)N * 32;           // [N,32]

    float* z_out  = (float*)d_out;               // [N,32]
    float* recon  = z_out + (long)N * 32;        // [N,128]

    const int B = 256;
    const int nb_scan = (N + 255) / 256;         // 196 (<=256, fits one scan2 block)

    // ---- graph preprocessing (per call; graph fixed but no cross-call state) ----
    hipMemsetAsync(cnt_out, 0, 2L * N * sizeof(int), stream);
    k_hist<<<(E + B - 1) / B, B, 0, stream>>>(src, dst, cnt_out, cnt_in, E);
    k_rsqrt_deg<<<(N + B - 1) / B, B, 0, stream>>>(cnt_out, cnt_in, rs_out, rs_in, N);
    k_scan1<<<nb_scan, B, 0, stream>>>(cnt_in, scan_p, blocksum, N);
    k_scan2<<<1, B, 0, stream>>>(blocksum, nb_scan);
    k_scan3<<<nb_scan, B, 0, stream>>>(cnt_in, scan_p, blocksum, row_ptr, cursor, N);
    k_fill<<<(E + B - 1) / B, B, 0, stream>>>(src, dst, cursor, csr_src, E);

    // ---- Layer 1: 128 -> 64 ----
    k_gemm_rowscale<128, 64, 16><<<(N + 15) / 16, B, 0, stream>>>(feat, W1, rs_out, nullptr, t1, N);
    k_gather<64, true, false, true><<<(N * 64 + B - 1) / B, B, 0, stream>>>(
        row_ptr, csr_src, t1, nullptr, rs_in, b1, h1, N);

    // ---- Layer 2: 64 -> 32 (z to d_out) ----
    k_gemm_rowscale<64, 32, 16><<<(N + 15) / 16, B, 0, stream>>>(h1, W2, rs_out, nullptr, t2, N);
    k_gather<32, false, false, true><<<(N * 32 + B - 1) / B, B, 0, stream>>>(
        row_ptr, csr_src, t2, nullptr, rs_in, b2, z_out, N);

    // ---- Layer 3: aggregate z (width 32, src-scaled), then expand 32 -> 128 ----
    k_gather<32, false, true, false><<<(N * 32 + B - 1) / B, B, 0, stream>>>(
        row_ptr, csr_src, z_out, rs_out, rs_in, nullptr, agg3, N);
    k_gemm_rowscale<32, 128, 16><<<(N + 15) / 16, B, 0, stream>>>(agg3, W3, nullptr, b3, recon, N);
}

// Round 3
// 276.765 us; speedup vs baseline: 4.4506x; 1.2270x over previous
//
#include <hip/hip_runtime.h>
#include <hip/hip_bf16.h>

// GraphAutoencoder: 3x GraphConv (DGL norm='both') on fixed graph.
// N=50000 nodes, E=600000 edges, widths 128 -> 64 -> 32 -> 128.
//
// R1: scatter-atomics were RMW-bound (485us, 64B writeback per 16B atomic).
// R2: CSR + gather (no atomics) -> 340us; top kernel k_hist (50us, 1.2M
//     global atomics, WRITE_SIZE 37MB for a 400KB array).
// R3: (a) LDS-binned histogram, zero global atomics; (b) register-tiled
//     float4 GEMMs (was 2 scalar LDS reads/FMA); (c) float4 gathers.
//
// Algebra: agg(X) @ W == agg(X @ W)  -> aggregate at the narrow width:
//   L1: t1 = rs_out .* (X @ W1);  h1 = relu(rs_in .* gather(t1) + b1)
//   L2: t2 = rs_out .* (h1 @ W2); z  = rs_in .* gather(t2) + b2       -> d_out[0:1.6M]
//   L3: agg3 = rs_in .* gather(rs_out[src] .* z); recon = agg3 @ W3 + b3 -> d_out[1.6M:8M]

#define HNB 4
#define HPB 16
#define HBIN 12500

__global__ __launch_bounds__(256) void k_hist_lds(
    const int* __restrict__ src, const int* __restrict__ dst,
    int* __restrict__ slab, int E)
{
    __shared__ int h[HBIN];
    const int which = blockIdx.x / (HNB * HPB);       // 0: src, 1: dst
    const int bin   = (blockIdx.x / HPB) % HNB;
    const int p     = blockIdx.x % HPB;
    const int* __restrict__ idx = which ? dst : src;

    for (int i = threadIdx.x; i < HBIN; i += 256) h[i] = 0;
    __syncthreads();

    const int lo = bin * HBIN;
    for (int i = p * 256 + threadIdx.x; i < E; i += HPB * 256) {
        int v = idx[i] - lo;
        if ((unsigned)v < (unsigned)HBIN) atomicAdd(&h[v], 1);
    }
    __syncthreads();

    int* out = slab + (long)blockIdx.x * HBIN;
    for (int i = threadIdx.x; i < HBIN; i += 256) out[i] = h[i];
}

__global__ __launch_bounds__(256) void k_deg_reduce(
    const int* __restrict__ slab, int* __restrict__ cnt_in,
    float* __restrict__ rs_out, float* __restrict__ rs_in, int N)
{
    const int i = blockIdx.x * 256 + threadIdx.x;
    if (i >= N) return;
    const int bin = i / HBIN;
    const int off = i - bin * HBIN;
    int so = 0, si = 0;
#pragma unroll
    for (int p = 0; p < HPB; ++p) {
        so += slab[((long)(bin * HPB + p)) * HBIN + off];
        si += slab[((long)(HNB * HPB + bin * HPB + p)) * HBIN + off];
    }
    cnt_in[i] = si;
    rs_out[i] = rsqrtf(fmaxf((float)so, 1.0f));
    rs_in[i]  = rsqrtf(fmaxf((float)si, 1.0f));
}

__global__ void k_scan1(const int* __restrict__ cnt, int* __restrict__ partial,
                        int* __restrict__ blocksum, int n) {
    __shared__ int tmp[256];
    const int tid = threadIdx.x;
    const int i = blockIdx.x * 256 + tid;
    int v = (i < n) ? cnt[i] : 0;
    tmp[tid] = v; __syncthreads();
    for (int off = 1; off < 256; off <<= 1) {
        int t = (tid >= off) ? tmp[tid - off] : 0;
        __syncthreads(); tmp[tid] += t; __syncthreads();
    }
    if (i < n) partial[i] = tmp[tid];
    if (tid == 255) blocksum[blockIdx.x] = tmp[255];
}

__global__ void k_scan2(int* __restrict__ blocksum, int nb) {  // nb<=256, one block
    __shared__ int tmp[256];
    const int tid = threadIdx.x;
    int v = (tid < nb) ? blocksum[tid] : 0;
    tmp[tid] = v; __syncthreads();
    for (int off = 1; off < 256; off <<= 1) {
        int t = (tid >= off) ? tmp[tid - off] : 0;
        __syncthreads(); tmp[tid] += t; __syncthreads();
    }
    if (tid < nb) blocksum[tid] = tmp[tid];
}

__global__ void k_scan3(const int* __restrict__ cnt, const int* __restrict__ partial,
                        const int* __restrict__ blocksum,
                        int* __restrict__ row_ptr, int* __restrict__ cursor, int n) {
    const int i = blockIdx.x * 256 + threadIdx.x;
    if (i < n) {
        const int base = (blockIdx.x > 0) ? blocksum[blockIdx.x - 1] : 0;
        const int incl = partial[i] + base;
        row_ptr[i + 1] = incl;
        cursor[i] = incl - cnt[i];
        if (i == 0) row_ptr[0] = 0;
    }
}

__global__ void k_fill(const int* __restrict__ src, const int* __restrict__ dst,
                       int* __restrict__ cursor, int* __restrict__ csr_src, int E) {
    int e = blockIdx.x * blockDim.x + threadIdx.x;
    if (e < E) {
        int pos = atomicAdd(&cursor[dst[e]], 1);
        csr_src[pos] = src[e];
    }
}

// ---------------- register-tiled GEMM ----------------
template <int IN_F, int OUT_F, int TM>
__global__ __launch_bounds__(256) void k_gemm_tiled(
    const float* __restrict__ X, const float* __restrict__ W,
    const float* __restrict__ rowscale, const float* __restrict__ bias,
    float* __restrict__ Y, int n)
{
    constexpr int CT  = OUT_F / 4;   // col-thread groups (float4 each)
    constexpr int RT  = 256 / CT;    // row-thread groups
    constexpr int RPT = TM / RT;     // rows per thread
    constexpr int XS  = IN_F + 4;    // padded sX stride (banks + 16B align)
    __shared__ float sW[IN_F * OUT_F];
    __shared__ float sX[TM * XS];
    const int tid = threadIdx.x;
    const int row0 = blockIdx.x * TM;

    for (int i = tid; i < IN_F * OUT_F / 4; i += 256)
        ((float4*)sW)[i] = ((const float4*)W)[i];
    for (int i = tid; i < TM * IN_F / 4; i += 256) {
        const int r  = i / (IN_F / 4);
        const int c4 = (i % (IN_F / 4)) * 4;
        const int gr = row0 + r;
        float4 v = make_float4(0.f, 0.f, 0.f, 0.f);
        if (gr < n) v = *(const float4*)(X + (long)gr * IN_F + c4);
        *(float4*)(sX + r * XS + c4) = v;
    }
    __syncthreads();

    const int tc = tid % CT;
    const int tr = tid / CT;
    float4 acc[RPT];
#pragma unroll
    for (int i = 0; i < RPT; ++i) acc[i] = make_float4(0.f, 0.f, 0.f, 0.f);

#pragma unroll 8
    for (int k = 0; k < IN_F; ++k) {
        const float4 w = *(const float4*)(sW + k * OUT_F + 4 * tc);
#pragma unroll
        for (int i = 0; i < RPT; ++i) {
            const float xv = sX[(tr + i * RT) * XS + k];
            acc[i].x += xv * w.x; acc[i].y += xv * w.y;
            acc[i].z += xv * w.z; acc[i].w += xv * w.w;
        }
    }

#pragma unroll
    for (int i = 0; i < RPT; ++i) {
        const int gr = row0 + tr + i * RT;
        if (gr < n) {
            float4 v = acc[i];
            if (rowscale) {
                const float s = rowscale[gr];
                v.x *= s; v.y *= s; v.z *= s; v.w *= s;
            }
            if (bias) {
                const float4 bb = *(const float4*)(bias + 4 * tc);
                v.x += bb.x; v.y += bb.y; v.z += bb.z; v.w += bb.w;
            }
            *(float4*)(Y + (long)gr * OUT_F + 4 * tc) = v;
        }
    }
}

// ---------------- CSR gather-aggregate (float4), fused epilogue ----------------
template <int F, bool RELU, bool SRCSCALE, bool HAS_BIAS>
__global__ __launch_bounds__(256) void k_gather4(
    const int* __restrict__ row_ptr, const int* __restrict__ csr_src,
    const float* __restrict__ X, const float* __restrict__ srcscale,
    const float* __restrict__ rs_in, const float* __restrict__ bias,
    float* __restrict__ O, int N)
{
    constexpr int L   = F / 4;     // lanes per node
    constexpr int NPB = 256 / L;   // nodes per block
    const int node = blockIdx.x * NPB + threadIdx.x / L;
    const int c4 = (threadIdx.x % L) * 4;
    if (node >= N) return;

    const int beg = row_ptr[node];
    const int end = row_ptr[node + 1];
    float4 a0 = make_float4(0.f, 0.f, 0.f, 0.f);
    float4 a1 = make_float4(0.f, 0.f, 0.f, 0.f);
    int j = beg;
    for (; j + 1 < end; j += 2) {
        const int s0 = csr_src[j];
        const int s1 = csr_src[j + 1];
        float4 v0 = *(const float4*)(X + (long)s0 * F + c4);
        float4 v1 = *(const float4*)(X + (long)s1 * F + c4);
        if (SRCSCALE) {
            const float q0 = srcscale[s0], q1 = srcscale[s1];
            v0.x *= q0; v0.y *= q0; v0.z *= q0; v0.w *= q0;
            v1.x *= q1; v1.y *= q1; v1.z *= q1; v1.w *= q1;
        }
        a0.x += v0.x; a0.y += v0.y; a0.z += v0.z; a0.w += v0.w;
        a1.x += v1.x; a1.y += v1.y; a1.z += v1.z; a1.w += v1.w;
    }
    if (j < end) {
        const int s = csr_src[j];
        float4 v = *(const float4*)(X + (long)s * F + c4);
        if (SRCSCALE) {
            const float q = srcscale[s];
            v.x *= q; v.y *= q; v.z *= q; v.w *= q;
        }
        a0.x += v.x; a0.y += v.y; a0.z += v.z; a0.w += v.w;
    }
    const float rs = rs_in[node];
    float4 r;
    r.x = (a0.x + a1.x) * rs; r.y = (a0.y + a1.y) * rs;
    r.z = (a0.z + a1.z) * rs; r.w = (a0.w + a1.w) * rs;
    if (HAS_BIAS) {
        const float4 bb = *(const float4*)(bias + c4);
        r.x += bb.x; r.y += bb.y; r.z += bb.z; r.w += bb.w;
    }
    if (RELU) {
        r.x = fmaxf(r.x, 0.f); r.y = fmaxf(r.y, 0.f);
        r.z = fmaxf(r.z, 0.f); r.w = fmaxf(r.w, 0.f);
    }
    *(float4*)(O + (long)node * F + c4) = r;
}

extern "C" void kernel_launch(void* const* d_in, const int* in_sizes, int n_in,
                              void* d_out, int out_size, void* d_ws, size_t ws_size,
                              hipStream_t stream) {
    const float* feat = (const float*)d_in[0];   // [N,128]
    const int*   src  = (const int*)d_in[1];     // [E]
    const int*   dst  = (const int*)d_in[2];     // [E]
    const float* W1   = (const float*)d_in[3];   // [128,64]
    const float* b1   = (const float*)d_in[4];   // [64]
    const float* W2   = (const float*)d_in[5];   // [64,32]
    const float* b2   = (const float*)d_in[6];   // [32]
    const float* W3   = (const float*)d_in[7];   // [32,128]
    const float* b3   = (const float*)d_in[8];   // [128]

    const int E = in_sizes[1];
    const int N = in_sizes[0] / 128;             // 50000

    // ---- workspace layout ----
    const long SLAB = 2L * HNB * HPB * HBIN;     // 1.6M ints = 6.4MB
    int* slab    = (int*)d_ws;                   // dead after k_deg_reduce
    int* row_ptr = slab + SLAB;                  // [N+1]
    int* cursor  = row_ptr + N + 1;              // [N]
    int* scan_p  = cursor + N;                   // [N]
    int* blocksum= scan_p + N;                   // [256]
    int* cnt_in  = blocksum + 256;               // [N]
    int* csr_src = cnt_in + N;                   // [E]
    float* rs_out = (float*)(csr_src + E);       // [N]
    float* rs_in  = rs_out + N;                  // [N]
    float* t1     = rs_in + N;                   // [N,64]
    float* h1     = t1 + (long)N * 64;           // [N,64]
    float* agg3   = h1 + (long)N * 64;           // [N,32]
    float* t2     = (float*)slab;                // [N,32] aliases dead slab (same size)

    float* z_out  = (float*)d_out;               // [N,32]
    float* recon  = z_out + (long)N * 32;        // [N,128]

    const int B = 256;
    const int nb_scan = (N + 255) / 256;         // 196

    // ---- graph preprocessing ----
    k_hist_lds<<<2 * HNB * HPB, B, 0, stream>>>(src, dst, slab, E);
    k_deg_reduce<<<nb_scan, B, 0, stream>>>(slab, cnt_in, rs_out, rs_in, N);
    k_scan1<<<nb_scan, B, 0, stream>>>(cnt_in, scan_p, blocksum, N);
    k_scan2<<<1, B, 0, stream>>>(blocksum, nb_scan);
    k_scan3<<<nb_scan, B, 0, stream>>>(cnt_in, scan_p, blocksum, row_ptr, cursor, N);
    k_fill<<<(E + B - 1) / B, B, 0, stream>>>(src, dst, cursor, csr_src, E);

    // ---- Layer 1: 128 -> 64 ----
    k_gemm_tiled<128, 64, 32><<<(N + 31) / 32, B, 0, stream>>>(feat, W1, rs_out, nullptr, t1, N);
    k_gather4<64, true, false, true><<<(N + 15) / 16, B, 0, stream>>>(
        row_ptr, csr_src, t1, nullptr, rs_in, b1, h1, N);

    // ---- Layer 2: 64 -> 32 (z to d_out) ----
    k_gemm_tiled<64, 32, 64><<<(N + 63) / 64, B, 0, stream>>>(h1, W2, rs_out, nullptr, t2, N);
    k_gather4<32, false, false, true><<<(N + 31) / 32, B, 0, stream>>>(
        row_ptr, csr_src, t2, nullptr, rs_in, b2, z_out, N);

    // ---- Layer 3: aggregate z (width 32, src-scaled), then expand 32 -> 128 ----
    k_gather4<32, false, true, false><<<(N + 31) / 32, B, 0, stream>>>(
        row_ptr, csr_src, z_out, rs_out, rs_in, nullptr, agg3, N);
    k_gemm_tiled<32, 128, 64><<<(N + 63) / 64, B, 0, stream>>>(agg3, W3, nullptr, b3, recon, N);
}

// Round 4
// 242.594 us; speedup vs baseline: 5.0775x; 1.1409x over previous
//
#include <hip/hip_runtime.h>
#include <hip/hip_bf16.h>

// GraphAutoencoder: 3x GraphConv (DGL norm='both') on fixed graph.
// N=50000 nodes, E=600000 edges, widths 128 -> 64 -> 32 -> 128.
//
// R1: scatter-atomics RMW-bound (485us; 64B writeback per 16B atomic group).
// R2: CSR + gather -> 340us; k_hist (global atomics) top at 50us.
// R3: LDS-binned hist REGRESSED (65us): 128 blocks, 4.7% occupancy, scalar
//     loads -> latency-bound. GEMM/gather tiling gained ~60us. Total 277us.
// R4: atomic-free 2D counting sort: 64 edge-partitions x 4 node-bins,
//     u16 count slab; reduce builds per-partition exclusive offsets in-place;
//     fill uses LDS cursors only. Zero global atomics anywhere.
//
// Algebra: agg(X) @ W == agg(X @ W)  -> aggregate at the narrow width:
//   L1: t1 = rs_out .* (X @ W1);  h1 = relu(rs_in .* gather(t1) + b1)
//   L2: t2 = rs_out .* (h1 @ W2); z  = rs_in .* gather(t2) + b2       -> d_out[0:1.6M]
//   L3: agg3 = rs_in .* gather(rs_out[src] .* z); recon = agg3 @ W3 + b3 -> d_out[1.6M:8M]

#define HNB 4          // node bins
#define HPB 64         // edge partitions
#define HBIN 12500     // nodes per bin (HNB*HBIN == N)
typedef unsigned short u16;

// slab layout: u16 slab[2][HNB][HPB][HBIN]; which=0 -> src counts, 1 -> dst.
// After k_reduce, the dst half holds per-partition EXCLUSIVE prefix offsets.

__global__ __launch_bounds__(256) void k_hist2(
    const int* __restrict__ src, const int* __restrict__ dst,
    u16* __restrict__ slab, int E, int slice)
{
    __shared__ int h[HBIN];
    const int which = blockIdx.x / (HNB * HPB);
    const int bin   = (blockIdx.x / HPB) % HNB;
    const int p     = blockIdx.x % HPB;
    const int* __restrict__ idx = which ? dst : src;

    for (int i = threadIdx.x; i < HBIN; i += 256) h[i] = 0;
    __syncthreads();

    const int lo  = bin * HBIN;
    const int beg = p * slice;
    const int fin = min(beg + slice, E);
    for (int i = beg + threadIdx.x * 4; i + 3 < fin; i += 1024) {
        const int4 v = *(const int4*)(idx + i);
        int u;
        u = v.x - lo; if ((unsigned)u < (unsigned)HBIN) atomicAdd(&h[u], 1);
        u = v.y - lo; if ((unsigned)u < (unsigned)HBIN) atomicAdd(&h[u], 1);
        u = v.z - lo; if ((unsigned)u < (unsigned)HBIN) atomicAdd(&h[u], 1);
        u = v.w - lo; if ((unsigned)u < (unsigned)HBIN) atomicAdd(&h[u], 1);
    }
    for (int i = beg + ((fin - beg) & ~3) + threadIdx.x; i < fin; i += 256) {
        int u = idx[i] - lo;
        if ((unsigned)u < (unsigned)HBIN) atomicAdd(&h[u], 1);
    }
    __syncthreads();

    // packed u16x2 flush (block offset = blockIdx.x*HBIN u16 = 25000B, 4B-aligned)
    unsigned* out = (unsigned*)(slab + (size_t)blockIdx.x * HBIN);
    for (int i = threadIdx.x; i < HBIN / 2; i += 256)
        out[i] = (unsigned)h[2 * i] | ((unsigned)h[2 * i + 1] << 16);
}

// Sum partials -> degrees (rsqrt) + cnt_in; overwrite dst half with exclusive
// per-partition offsets (in-place, each thread owns one node column).
__global__ __launch_bounds__(256) void k_reduce2(
    u16* __restrict__ slab, int* __restrict__ cnt_in,
    float* __restrict__ rs_out, float* __restrict__ rs_in, int N)
{
    const int i = blockIdx.x * 256 + threadIdx.x;
    if (i >= N) return;
    const int bin = i / HBIN;
    const int off = i - bin * HBIN;

    const u16* s_src = slab + ((size_t)(bin * HPB)) * HBIN + off;
    u16*       s_dst = slab + ((size_t)((HNB + bin) * HPB)) * HBIN + off;

    int so = 0;
#pragma unroll
    for (int p = 0; p < HPB; ++p) so += s_src[(size_t)p * HBIN];

    int run = 0;
#pragma unroll
    for (int p = 0; p < HPB; ++p) {
        const int c = s_dst[(size_t)p * HBIN];
        s_dst[(size_t)p * HBIN] = (u16)run;
        run += c;
    }
    cnt_in[i] = run;
    rs_out[i] = rsqrtf(fmaxf((float)so, 1.0f));
    rs_in[i]  = rsqrtf(fmaxf((float)run, 1.0f));
}

// ---------- scan of cnt_in -> row_ptr ----------
__global__ void k_scan1(const int* __restrict__ cnt, int* __restrict__ partial,
                        int* __restrict__ blocksum, int n) {
    __shared__ int tmp[256];
    const int tid = threadIdx.x;
    const int i = blockIdx.x * 256 + tid;
    int v = (i < n) ? cnt[i] : 0;
    tmp[tid] = v; __syncthreads();
    for (int off = 1; off < 256; off <<= 1) {
        int t = (tid >= off) ? tmp[tid - off] : 0;
        __syncthreads(); tmp[tid] += t; __syncthreads();
    }
    if (i < n) partial[i] = tmp[tid];
    if (tid == 255) blocksum[blockIdx.x] = tmp[255];
}

__global__ void k_scan2(int* __restrict__ blocksum, int nb) {  // nb<=256
    __shared__ int tmp[256];
    const int tid = threadIdx.x;
    int v = (tid < nb) ? blocksum[tid] : 0;
    tmp[tid] = v; __syncthreads();
    for (int off = 1; off < 256; off <<= 1) {
        int t = (tid >= off) ? tmp[tid - off] : 0;
        __syncthreads(); tmp[tid] += t; __syncthreads();
    }
    if (tid < nb) blocksum[tid] = tmp[tid];
}

__global__ void k_scan3(const int* __restrict__ partial, const int* __restrict__ blocksum,
                        int* __restrict__ row_ptr, int n) {
    const int i = blockIdx.x * 256 + threadIdx.x;
    if (i < n) {
        const int base = (blockIdx.x > 0) ? blocksum[blockIdx.x - 1] : 0;
        row_ptr[i + 1] = partial[i] + base;
        if (i == 0) row_ptr[0] = 0;
    }
}

// ---------- CSR fill: LDS cursors seeded from row_ptr + per-part offsets ----------
__global__ __launch_bounds__(256) void k_fill2(
    const int* __restrict__ src, const int* __restrict__ dst,
    const int* __restrict__ row_ptr, const u16* __restrict__ slab,
    int* __restrict__ csr_src, int E, int slice, int N)
{
    __shared__ int cur[HBIN];
    const int bin = blockIdx.x / HPB;
    const int p   = blockIdx.x % HPB;
    const int lo  = bin * HBIN;

    const u16* part_off = slab + ((size_t)((HNB + bin) * HPB + p)) * HBIN;
    for (int j = threadIdx.x; j < HBIN; j += 256) {
        const int node = lo + j;
        cur[j] = (node < N) ? (row_ptr[node] + (int)part_off[j]) : 0;
    }
    __syncthreads();

    const int beg = p * slice;
    const int fin = min(beg + slice, E);
    for (int i = beg + threadIdx.x * 4; i + 3 < fin; i += 1024) {
        const int4 d = *(const int4*)(dst + i);
        const int4 s = *(const int4*)(src + i);
        int u;
        u = d.x - lo; if ((unsigned)u < (unsigned)HBIN) csr_src[atomicAdd(&cur[u], 1)] = s.x;
        u = d.y - lo; if ((unsigned)u < (unsigned)HBIN) csr_src[atomicAdd(&cur[u], 1)] = s.y;
        u = d.z - lo; if ((unsigned)u < (unsigned)HBIN) csr_src[atomicAdd(&cur[u], 1)] = s.z;
        u = d.w - lo; if ((unsigned)u < (unsigned)HBIN) csr_src[atomicAdd(&cur[u], 1)] = s.w;
    }
    for (int i = beg + ((fin - beg) & ~3) + threadIdx.x; i < fin; i += 256) {
        int u = dst[i] - lo;
        if ((unsigned)u < (unsigned)HBIN) csr_src[atomicAdd(&cur[u], 1)] = src[i];
    }
}

// ---------------- register-tiled GEMM ----------------
template <int IN_F, int OUT_F, int TM>
__global__ __launch_bounds__(256) void k_gemm_tiled(
    const float* __restrict__ X, const float* __restrict__ W,
    const float* __restrict__ rowscale, const float* __restrict__ bias,
    float* __restrict__ Y, int n)
{
    constexpr int CT  = OUT_F / 4;
    constexpr int RT  = 256 / CT;
    constexpr int RPT = TM / RT;
    constexpr int XS  = IN_F + 4;
    __shared__ float sW[IN_F * OUT_F];
    __shared__ float sX[TM * XS];
    const int tid = threadIdx.x;
    const int row0 = blockIdx.x * TM;

    for (int i = tid; i < IN_F * OUT_F / 4; i += 256)
        ((float4*)sW)[i] = ((const float4*)W)[i];
    for (int i = tid; i < TM * IN_F / 4; i += 256) {
        const int r  = i / (IN_F / 4);
        const int c4 = (i % (IN_F / 4)) * 4;
        const int gr = row0 + r;
        float4 v = make_float4(0.f, 0.f, 0.f, 0.f);
        if (gr < n) v = *(const float4*)(X + (long)gr * IN_F + c4);
        *(float4*)(sX + r * XS + c4) = v;
    }
    __syncthreads();

    const int tc = tid % CT;
    const int tr = tid / CT;
    float4 acc[RPT];
#pragma unroll
    for (int i = 0; i < RPT; ++i) acc[i] = make_float4(0.f, 0.f, 0.f, 0.f);

#pragma unroll 8
    for (int k = 0; k < IN_F; ++k) {
        const float4 w = *(const float4*)(sW + k * OUT_F + 4 * tc);
#pragma unroll
        for (int i = 0; i < RPT; ++i) {
            const float xv = sX[(tr + i * RT) * XS + k];
            acc[i].x += xv * w.x; acc[i].y += xv * w.y;
            acc[i].z += xv * w.z; acc[i].w += xv * w.w;
        }
    }

#pragma unroll
    for (int i = 0; i < RPT; ++i) {
        const int gr = row0 + tr + i * RT;
        if (gr < n) {
            float4 v = acc[i];
            if (rowscale) {
                const float s = rowscale[gr];
                v.x *= s; v.y *= s; v.z *= s; v.w *= s;
            }
            if (bias) {
                const float4 bb = *(const float4*)(bias + 4 * tc);
                v.x += bb.x; v.y += bb.y; v.z += bb.z; v.w += bb.w;
            }
            *(float4*)(Y + (long)gr * OUT_F + 4 * tc) = v;
        }
    }
}

// ---------------- CSR gather-aggregate (float4), fused epilogue ----------------
template <int F, bool RELU, bool SRCSCALE, bool HAS_BIAS>
__global__ __launch_bounds__(256) void k_gather4(
    const int* __restrict__ row_ptr, const int* __restrict__ csr_src,
    const float* __restrict__ X, const float* __restrict__ srcscale,
    const float* __restrict__ rs_in, const float* __restrict__ bias,
    float* __restrict__ O, int N)
{
    constexpr int L   = F / 4;
    constexpr int NPB = 256 / L;
    const int node = blockIdx.x * NPB + threadIdx.x / L;
    const int c4 = (threadIdx.x % L) * 4;
    if (node >= N) return;

    const int beg = row_ptr[node];
    const int end = row_ptr[node + 1];
    float4 a0 = make_float4(0.f, 0.f, 0.f, 0.f);
    float4 a1 = make_float4(0.f, 0.f, 0.f, 0.f);
    int j = beg;
    for (; j + 1 < end; j += 2) {
        const int s0 = csr_src[j];
        const int s1 = csr_src[j + 1];
        float4 v0 = *(const float4*)(X + (long)s0 * F + c4);
        float4 v1 = *(const float4*)(X + (long)s1 * F + c4);
        if (SRCSCALE) {
            const float q0 = srcscale[s0], q1 = srcscale[s1];
            v0.x *= q0; v0.y *= q0; v0.z *= q0; v0.w *= q0;
            v1.x *= q1; v1.y *= q1; v1.z *= q1; v1.w *= q1;
        }
        a0.x += v0.x; a0.y += v0.y; a0.z += v0.z; a0.w += v0.w;
        a1.x += v1.x; a1.y += v1.y; a1.z += v1.z; a1.w += v1.w;
    }
    if (j < end) {
        const int s = csr_src[j];
        float4 v = *(const float4*)(X + (long)s * F + c4);
        if (SRCSCALE) {
            const float q = srcscale[s];
            v.x *= q; v.y *= q; v.z *= q; v.w *= q;
        }
        a0.x += v.x; a0.y += v.y; a0.z += v.z; a0.w += v.w;
    }
    const float rs = rs_in[node];
    float4 r;
    r.x = (a0.x + a1.x) * rs; r.y = (a0.y + a1.y) * rs;
    r.z = (a0.z + a1.z) * rs; r.w = (a0.w + a1.w) * rs;
    if (HAS_BIAS) {
        const float4 bb = *(const float4*)(bias + c4);
        r.x += bb.x; r.y += bb.y; r.z += bb.z; r.w += bb.w;
    }
    if (RELU) {
        r.x = fmaxf(r.x, 0.f); r.y = fmaxf(r.y, 0.f);
        r.z = fmaxf(r.z, 0.f); r.w = fmaxf(r.w, 0.f);
    }
    *(float4*)(O + (long)node * F + c4) = r;
}

extern "C" void kernel_launch(void* const* d_in, const int* in_sizes, int n_in,
                              void* d_out, int out_size, void* d_ws, size_t ws_size,
                              hipStream_t stream) {
    const float* feat = (const float*)d_in[0];   // [N,128]
    const int*   src  = (const int*)d_in[1];     // [E]
    const int*   dst  = (const int*)d_in[2];     // [E]
    const float* W1   = (const float*)d_in[3];   // [128,64]
    const float* b1   = (const float*)d_in[4];   // [64]
    const float* W2   = (const float*)d_in[5];   // [64,32]
    const float* b2   = (const float*)d_in[6];   // [32]
    const float* W3   = (const float*)d_in[7];   // [32,128]
    const float* b3   = (const float*)d_in[8];   // [128]

    const int E = in_sizes[1];
    const int N = in_sizes[0] / 128;             // 50000 == HNB*HBIN
    const int slice = (((E + HPB - 1) / HPB) + 3) & ~3;  // 16B-aligned edge slices

    // ---- workspace layout ----
    const size_t SLABN = 2UL * HNB * HPB * HBIN;  // 6.4M u16 = 12.8MB
    u16* slab     = (u16*)d_ws;                   // dead after k_fill2
    int* row_ptr  = (int*)(slab + SLABN);         // [N+1]
    int* scan_p   = row_ptr + N + 1;              // [N]
    int* blocksum = scan_p + N;                   // [256]
    int* cnt_in   = blocksum + 256;               // [N]
    int* csr_src  = cnt_in + N;                   // [E]
    float* rs_out = (float*)(csr_src + E);        // [N]
    float* rs_in  = rs_out + N;                   // [N]
    float* h1     = rs_in + N;                    // [N,64]
    float* t2     = h1 + (long)N * 64;            // [N,32]
    float* agg3   = t2 + (long)N * 32;            // [N,32]
    float* t1     = (float*)slab;                 // [N,64] = 12.8MB, aliases dead slab

    float* z_out  = (float*)d_out;                // [N,32]
    float* recon  = z_out + (long)N * 32;         // [N,128]

    const int B = 256;
    const int nb_scan = (N + 255) / 256;          // 196

    // ---- atomic-free graph preprocessing ----
    k_hist2<<<2 * HNB * HPB, B, 0, stream>>>(src, dst, slab, E, slice);
    k_reduce2<<<nb_scan, B, 0, stream>>>(slab, cnt_in, rs_out, rs_in, N);
    k_scan1<<<nb_scan, B, 0, stream>>>(cnt_in, scan_p, blocksum, N);
    k_scan2<<<1, B, 0, stream>>>(blocksum, nb_scan);
    k_scan3<<<nb_scan, B, 0, stream>>>(scan_p, blocksum, row_ptr, N);
    k_fill2<<<HNB * HPB, B, 0, stream>>>(src, dst, row_ptr, slab, csr_src, E, slice, N);

    // ---- Layer 1: 128 -> 64 (t1 overwrites slab: fill is complete) ----
    k_gemm_tiled<128, 64, 32><<<(N + 31) / 32, B, 0, stream>>>(feat, W1, rs_out, nullptr, t1, N);
    k_gather4<64, true, false, true><<<(N + 15) / 16, B, 0, stream>>>(
        row_ptr, csr_src, t1, nullptr, rs_in, b1, h1, N);

    // ---- Layer 2: 64 -> 32 (z to d_out) ----
    k_gemm_tiled<64, 32, 64><<<(N + 63) / 64, B, 0, stream>>>(h1, W2, rs_out, nullptr, t2, N);
    k_gather4<32, false, false, true><<<(N + 31) / 32, B, 0, stream>>>(
        row_ptr, csr_src, t2, nullptr, rs_in, b2, z_out, N);

    // ---- Layer 3: aggregate z (src-scaled), then expand 32 -> 128 ----
    k_gather4<32, false, true, false><<<(N + 31) / 32, B, 0, stream>>>(
        row_ptr, csr_src, z_out, rs_out, rs_in, nullptr, agg3, N);
    k_gemm_tiled<32, 128, 64><<<(N + 63) / 64, B, 0, stream>>>(agg3, W3, nullptr, b3, recon, N);
}

// Round 5
// 223.134 us; speedup vs baseline: 5.5203x; 1.0872x over previous
//
#include <hip/hip_runtime.h>
#include <hip/hip_bf16.h>

// GraphAutoencoder: 3x GraphConv (DGL norm='both') on fixed graph.
// N=50000 nodes, E=600000 edges, widths 128 -> 64 -> 32 -> 128.
//
// R1: scatter-atomics RMW-bound (485us). R2: CSR+gather -> 340us.
// R3: tiled GEMM/gathers -> 277us (LDS hist regressed: occupancy).
// R4: atomic-free 2D counting sort -> 243us. Harness 0xAA poison of the
//     256MiB ws (fillBufferAligned, 42us) is INSIDE the timed window —
//     fixed floor; controllable budget ~200us, gathers dominate.
// R5: bf16 gather sources (t1,t2,zb), f32 accumulate. Layer-3 srcscale
//     folded into a pre-scaled bf16 shadow zb = z*rs_out written by
//     gather2's epilogue. 4-deep edge unroll. Random-read bytes halved.
//
// Algebra: agg(X) @ W == agg(X @ W)  -> aggregate at the narrow width:
//   L1: t1b = bf16(rs_out .* (X @ W1));  h1 = relu(rs_in .* gather(t1b) + b1)   [h1 f32]
//   L2: t2b = bf16(rs_out .* (h1 @ W2)); z = rs_in .* gather(t2b) + b2 -> d_out
//       zb = bf16(z .* rs_out)                                          [shadow]
//   L3: agg3 = rs_in .* gather(zb); recon = agg3 @ W3 + b3 -> d_out[1.6M:8M]

#define HNB 4          // node bins
#define HPB 64         // edge partitions
#define HBIN 12500     // nodes per bin (HNB*HBIN == N)
typedef unsigned short u16;

__device__ __forceinline__ float bfhi(unsigned u) {   // high u16 -> f32
    unsigned v = u & 0xFFFF0000u;
    return __builtin_bit_cast(float, v);
}
__device__ __forceinline__ float bflo(unsigned u) {   // low u16 -> f32
    unsigned v = u << 16;
    return __builtin_bit_cast(float, v);
}
__device__ __forceinline__ unsigned f2bf(float f) {   // f32 -> bf16 (RNE), in low 16
    unsigned u = __builtin_bit_cast(unsigned, f);
    return (u + 0x7FFFu + ((u >> 16) & 1u)) >> 16;
}

// ---------------- histogram: u16 slab[2][HNB][HPB][HBIN] ----------------
__global__ __launch_bounds__(256) void k_hist2(
    const int* __restrict__ src, const int* __restrict__ dst,
    u16* __restrict__ slab, int E, int slice)
{
    __shared__ int h[HBIN];
    const int which = blockIdx.x / (HNB * HPB);
    const int bin   = (blockIdx.x / HPB) % HNB;
    const int p     = blockIdx.x % HPB;
    const int* __restrict__ idx = which ? dst : src;

    for (int i = threadIdx.x; i < HBIN; i += 256) h[i] = 0;
    __syncthreads();

    const int lo  = bin * HBIN;
    const int beg = p * slice;
    const int fin = min(beg + slice, E);
    for (int i = beg + threadIdx.x * 4; i + 3 < fin; i += 1024) {
        const int4 v = *(const int4*)(idx + i);
        int u;
        u = v.x - lo; if ((unsigned)u < (unsigned)HBIN) atomicAdd(&h[u], 1);
        u = v.y - lo; if ((unsigned)u < (unsigned)HBIN) atomicAdd(&h[u], 1);
        u = v.z - lo; if ((unsigned)u < (unsigned)HBIN) atomicAdd(&h[u], 1);
        u = v.w - lo; if ((unsigned)u < (unsigned)HBIN) atomicAdd(&h[u], 1);
    }
    for (int i = beg + ((fin - beg) & ~3) + threadIdx.x; i < fin; i += 256) {
        int u = idx[i] - lo;
        if ((unsigned)u < (unsigned)HBIN) atomicAdd(&h[u], 1);
    }
    __syncthreads();

    unsigned* out = (unsigned*)(slab + (size_t)blockIdx.x * HBIN);
    for (int i = threadIdx.x; i < HBIN / 2; i += 256)
        out[i] = (unsigned)h[2 * i] | ((unsigned)h[2 * i + 1] << 16);
}

// degrees -> rsqrt + cnt_in; dst half overwritten with per-partition excl offsets
__global__ __launch_bounds__(256) void k_reduce2(
    u16* __restrict__ slab, int* __restrict__ cnt_in,
    float* __restrict__ rs_out, float* __restrict__ rs_in, int N)
{
    const int i = blockIdx.x * 256 + threadIdx.x;
    if (i >= N) return;
    const int bin = i / HBIN;
    const int off = i - bin * HBIN;

    const u16* s_src = slab + ((size_t)(bin * HPB)) * HBIN + off;
    u16*       s_dst = slab + ((size_t)((HNB + bin) * HPB)) * HBIN + off;

    int so = 0;
#pragma unroll
    for (int p = 0; p < HPB; ++p) so += s_src[(size_t)p * HBIN];

    int run = 0;
#pragma unroll
    for (int p = 0; p < HPB; ++p) {
        const int c = s_dst[(size_t)p * HBIN];
        s_dst[(size_t)p * HBIN] = (u16)run;
        run += c;
    }
    cnt_in[i] = run;
    rs_out[i] = rsqrtf(fmaxf((float)so, 1.0f));
    rs_in[i]  = rsqrtf(fmaxf((float)run, 1.0f));
}

// ---------- scan of cnt_in -> row_ptr ----------
__global__ void k_scan1(const int* __restrict__ cnt, int* __restrict__ partial,
                        int* __restrict__ blocksum, int n) {
    __shared__ int tmp[256];
    const int tid = threadIdx.x;
    const int i = blockIdx.x * 256 + tid;
    int v = (i < n) ? cnt[i] : 0;
    tmp[tid] = v; __syncthreads();
    for (int off = 1; off < 256; off <<= 1) {
        int t = (tid >= off) ? tmp[tid - off] : 0;
        __syncthreads(); tmp[tid] += t; __syncthreads();
    }
    if (i < n) partial[i] = tmp[tid];
    if (tid == 255) blocksum[blockIdx.x] = tmp[255];
}

__global__ void k_scan2(int* __restrict__ blocksum, int nb) {  // nb<=256
    __shared__ int tmp[256];
    const int tid = threadIdx.x;
    int v = (tid < nb) ? blocksum[tid] : 0;
    tmp[tid] = v; __syncthreads();
    for (int off = 1; off < 256; off <<= 1) {
        int t = (tid >= off) ? tmp[tid - off] : 0;
        __syncthreads(); tmp[tid] += t; __syncthreads();
    }
    if (tid < nb) blocksum[tid] = tmp[tid];
}

__global__ void k_scan3(const int* __restrict__ partial, const int* __restrict__ blocksum,
                        int* __restrict__ row_ptr, int n) {
    const int i = blockIdx.x * 256 + threadIdx.x;
    if (i < n) {
        const int base = (blockIdx.x > 0) ? blocksum[blockIdx.x - 1] : 0;
        row_ptr[i + 1] = partial[i] + base;
        if (i == 0) row_ptr[0] = 0;
    }
}

// ---------- CSR fill: LDS cursors (zero global atomics) ----------
__global__ __launch_bounds__(256) void k_fill2(
    const int* __restrict__ src, const int* __restrict__ dst,
    const int* __restrict__ row_ptr, const u16* __restrict__ slab,
    int* __restrict__ csr_src, int E, int slice, int N)
{
    __shared__ int cur[HBIN];
    const int bin = blockIdx.x / HPB;
    const int p   = blockIdx.x % HPB;
    const int lo  = bin * HBIN;

    const u16* part_off = slab + ((size_t)((HNB + bin) * HPB + p)) * HBIN;
    for (int j = threadIdx.x; j < HBIN; j += 256) {
        const int node = lo + j;
        cur[j] = (node < N) ? (row_ptr[node] + (int)part_off[j]) : 0;
    }
    __syncthreads();

    const int beg = p * slice;
    const int fin = min(beg + slice, E);
    for (int i = beg + threadIdx.x * 4; i + 3 < fin; i += 1024) {
        const int4 d = *(const int4*)(dst + i);
        const int4 s = *(const int4*)(src + i);
        int u;
        u = d.x - lo; if ((unsigned)u < (unsigned)HBIN) csr_src[atomicAdd(&cur[u], 1)] = s.x;
        u = d.y - lo; if ((unsigned)u < (unsigned)HBIN) csr_src[atomicAdd(&cur[u], 1)] = s.y;
        u = d.z - lo; if ((unsigned)u < (unsigned)HBIN) csr_src[atomicAdd(&cur[u], 1)] = s.z;
        u = d.w - lo; if ((unsigned)u < (unsigned)HBIN) csr_src[atomicAdd(&cur[u], 1)] = s.w;
    }
    for (int i = beg + ((fin - beg) & ~3) + threadIdx.x; i < fin; i += 256) {
        int u = dst[i] - lo;
        if ((unsigned)u < (unsigned)HBIN) csr_src[atomicAdd(&cur[u], 1)] = src[i];
    }
}

// ---------------- register-tiled GEMM, optional bf16 output ----------------
template <int IN_F, int OUT_F, int TM, bool OUT_BF16>
__global__ __launch_bounds__(256) void k_gemm_tiled(
    const float* __restrict__ X, const float* __restrict__ W,
    const float* __restrict__ rowscale, const float* __restrict__ bias,
    void* __restrict__ Y, int n)
{
    constexpr int CT  = OUT_F / 4;
    constexpr int RT  = 256 / CT;
    constexpr int RPT = TM / RT;
    constexpr int XS  = IN_F + 4;
    __shared__ float sW[IN_F * OUT_F];
    __shared__ float sX[TM * XS];
    const int tid = threadIdx.x;
    const int row0 = blockIdx.x * TM;

    for (int i = tid; i < IN_F * OUT_F / 4; i += 256)
        ((float4*)sW)[i] = ((const float4*)W)[i];
    for (int i = tid; i < TM * IN_F / 4; i += 256) {
        const int r  = i / (IN_F / 4);
        const int c4 = (i % (IN_F / 4)) * 4;
        const int gr = row0 + r;
        float4 v = make_float4(0.f, 0.f, 0.f, 0.f);
        if (gr < n) v = *(const float4*)(X + (long)gr * IN_F + c4);
        *(float4*)(sX + r * XS + c4) = v;
    }
    __syncthreads();

    const int tc = tid % CT;
    const int tr = tid / CT;
    float4 acc[RPT];
#pragma unroll
    for (int i = 0; i < RPT; ++i) acc[i] = make_float4(0.f, 0.f, 0.f, 0.f);

#pragma unroll 8
    for (int k = 0; k < IN_F; ++k) {
        const float4 w = *(const float4*)(sW + k * OUT_F + 4 * tc);
#pragma unroll
        for (int i = 0; i < RPT; ++i) {
            const float xv = sX[(tr + i * RT) * XS + k];
            acc[i].x += xv * w.x; acc[i].y += xv * w.y;
            acc[i].z += xv * w.z; acc[i].w += xv * w.w;
        }
    }

#pragma unroll
    for (int i = 0; i < RPT; ++i) {
        const int gr = row0 + tr + i * RT;
        if (gr < n) {
            float4 v = acc[i];
            if (rowscale) {
                const float s = rowscale[gr];
                v.x *= s; v.y *= s; v.z *= s; v.w *= s;
            }
            if (bias) {
                const float4 bb = *(const float4*)(bias + 4 * tc);
                v.x += bb.x; v.y += bb.y; v.z += bb.z; v.w += bb.w;
            }
            if (OUT_BF16) {
                uint2 pk;
                pk.x = f2bf(v.x) | (f2bf(v.y) << 16);
                pk.y = f2bf(v.z) | (f2bf(v.w) << 16);
                *(uint2*)((u16*)Y + (size_t)gr * OUT_F + 4 * tc) = pk;
            } else {
                *(float4*)((float*)Y + (size_t)gr * OUT_F + 4 * tc) = v;
            }
        }
    }
}

// ---------------- CSR gather (bf16 source), fused epilogue ----------------
// O[d,:] = op( rs_in[d] * sum_j Xb[csr_src[j],:] + bias? )   [f32 out]
// SHADOW: also write Osh[d,:] = bf16(O_pre_relu... actually post) * rs_sh[d]
template <int F, bool RELU, bool HAS_BIAS, bool SHADOW>
__global__ __launch_bounds__(256) void k_gather_b(
    const int* __restrict__ row_ptr, const int* __restrict__ csr_src,
    const u16* __restrict__ Xb, const float* __restrict__ rs_in,
    const float* __restrict__ rs_sh, const float* __restrict__ bias,
    float* __restrict__ O, u16* __restrict__ Osh, int N)
{
    constexpr int L   = F / 8;     // lanes per node (8 bf16 = 16B per lane)
    constexpr int NPB = 256 / L;
    const int node = blockIdx.x * NPB + threadIdx.x / L;
    const int c8 = (threadIdx.x % L) * 8;
    if (node >= N) return;

    const int beg = row_ptr[node];
    const int end = row_ptr[node + 1];
    float a[8];
#pragma unroll
    for (int t = 0; t < 8; ++t) a[t] = 0.f;

    int j = beg;
    for (; j + 3 < end; j += 4) {
        const int s0 = csr_src[j], s1 = csr_src[j + 1];
        const int s2 = csr_src[j + 2], s3 = csr_src[j + 3];
        const uint4 q0 = *(const uint4*)(Xb + (size_t)s0 * F + c8);
        const uint4 q1 = *(const uint4*)(Xb + (size_t)s1 * F + c8);
        const uint4 q2 = *(const uint4*)(Xb + (size_t)s2 * F + c8);
        const uint4 q3 = *(const uint4*)(Xb + (size_t)s3 * F + c8);
        a[0] += bflo(q0.x); a[1] += bfhi(q0.x); a[2] += bflo(q0.y); a[3] += bfhi(q0.y);
        a[4] += bflo(q0.z); a[5] += bfhi(q0.z); a[6] += bflo(q0.w); a[7] += bfhi(q0.w);
        a[0] += bflo(q1.x); a[1] += bfhi(q1.x); a[2] += bflo(q1.y); a[3] += bfhi(q1.y);
        a[4] += bflo(q1.z); a[5] += bfhi(q1.z); a[6] += bflo(q1.w); a[7] += bfhi(q1.w);
        a[0] += bflo(q2.x); a[1] += bfhi(q2.x); a[2] += bflo(q2.y); a[3] += bfhi(q2.y);
        a[4] += bflo(q2.z); a[5] += bfhi(q2.z); a[6] += bflo(q2.w); a[7] += bfhi(q2.w);
        a[0] += bflo(q3.x); a[1] += bfhi(q3.x); a[2] += bflo(q3.y); a[3] += bfhi(q3.y);
        a[4] += bflo(q3.z); a[5] += bfhi(q3.z); a[6] += bflo(q3.w); a[7] += bfhi(q3.w);
    }
    for (; j < end; ++j) {
        const int s = csr_src[j];
        const uint4 q = *(const uint4*)(Xb + (size_t)s * F + c8);
        a[0] += bflo(q.x); a[1] += bfhi(q.x); a[2] += bflo(q.y); a[3] += bfhi(q.y);
        a[4] += bflo(q.z); a[5] += bfhi(q.z); a[6] += bflo(q.w); a[7] += bfhi(q.w);
    }

    const float rs = rs_in[node];
    float v[8];
#pragma unroll
    for (int t = 0; t < 8; ++t) v[t] = a[t] * rs;
    if (HAS_BIAS) {
        const float4 b0 = *(const float4*)(bias + c8);
        const float4 b1 = *(const float4*)(bias + c8 + 4);
        v[0] += b0.x; v[1] += b0.y; v[2] += b0.z; v[3] += b0.w;
        v[4] += b1.x; v[5] += b1.y; v[6] += b1.z; v[7] += b1.w;
    }
    if (RELU) {
#pragma unroll
        for (int t = 0; t < 8; ++t) v[t] = fmaxf(v[t], 0.f);
    }
    float* o = O + (size_t)node * F + c8;
    *(float4*)(o)     = make_float4(v[0], v[1], v[2], v[3]);
    *(float4*)(o + 4) = make_float4(v[4], v[5], v[6], v[7]);

    if (SHADOW) {
        const float ss = rs_sh[node];
        uint4 pk;
        pk.x = f2bf(v[0] * ss) | (f2bf(v[1] * ss) << 16);
        pk.y = f2bf(v[2] * ss) | (f2bf(v[3] * ss) << 16);
        pk.z = f2bf(v[4] * ss) | (f2bf(v[5] * ss) << 16);
        pk.w = f2bf(v[6] * ss) | (f2bf(v[7] * ss) << 16);
        *(uint4*)(Osh + (size_t)node * F + c8) = pk;
    }
}

extern "C" void kernel_launch(void* const* d_in, const int* in_sizes, int n_in,
                              void* d_out, int out_size, void* d_ws, size_t ws_size,
                              hipStream_t stream) {
    const float* feat = (const float*)d_in[0];   // [N,128]
    const int*   src  = (const int*)d_in[1];     // [E]
    const int*   dst  = (const int*)d_in[2];     // [E]
    const float* W1   = (const float*)d_in[3];   // [128,64]
    const float* b1   = (const float*)d_in[4];   // [64]
    const float* W2   = (const float*)d_in[5];   // [64,32]
    const float* b2   = (const float*)d_in[6];   // [32]
    const float* W3   = (const float*)d_in[7];   // [32,128]
    const float* b3   = (const float*)d_in[8];   // [128]

    const int E = in_sizes[1];
    const int N = in_sizes[0] / 128;             // 50000 == HNB*HBIN
    const int slice = (((E + HPB - 1) / HPB) + 3) & ~3;

    // ---- workspace layout (16B alignment preserved at every boundary) ----
    const size_t SLABN = 2UL * HNB * HPB * HBIN;  // 6.4M u16 = 12.8MB
    u16* slab     = (u16*)d_ws;                   // dead after k_fill2
    int* row_ptr  = (int*)(slab + SLABN);         // [N+16] (padded for alignment)
    int* scan_p   = row_ptr + N + 16;             // [N]
    int* blocksum = scan_p + N;                   // [256]
    int* cnt_in   = blocksum + 256;               // [N]
    int* csr_src  = cnt_in + N;                   // [E]
    float* rs_out = (float*)(csr_src + E);        // [N]
    float* rs_in  = rs_out + N;                   // [N]
    float* h1     = rs_in + N;                    // [N,64] f32
    u16* t2b      = (u16*)(h1 + (size_t)N * 64);  // [N,32] bf16
    u16* zb       = t2b + (size_t)N * 32;         // [N,32] bf16 (z * rs_out)
    float* agg3   = (float*)(zb + (size_t)N * 32);// [N,32] f32
    u16* t1b      = (u16*)slab;                   // [N,64] bf16, aliases dead slab

    float* z_out  = (float*)d_out;                // [N,32]
    float* recon  = z_out + (size_t)N * 32;       // [N,128]

    const int B = 256;
    const int nb_scan = (N + 255) / 256;          // 196

    // ---- atomic-free graph preprocessing ----
    k_hist2<<<2 * HNB * HPB, B, 0, stream>>>(src, dst, slab, E, slice);
    k_reduce2<<<nb_scan, B, 0, stream>>>(slab, cnt_in, rs_out, rs_in, N);
    k_scan1<<<nb_scan, B, 0, stream>>>(cnt_in, scan_p, blocksum, N);
    k_scan2<<<1, B, 0, stream>>>(blocksum, nb_scan);
    k_scan3<<<nb_scan, B, 0, stream>>>(scan_p, blocksum, row_ptr, N);
    k_fill2<<<HNB * HPB, B, 0, stream>>>(src, dst, row_ptr, slab, csr_src, E, slice, N);

    // ---- Layer 1: 128 -> 64 (t1b overwrites slab after fill) ----
    k_gemm_tiled<128, 64, 32, true><<<(N + 31) / 32, B, 0, stream>>>(
        feat, W1, rs_out, nullptr, t1b, N);
    k_gather_b<64, true, true, false><<<(N + 31) / 32, B, 0, stream>>>(
        row_ptr, csr_src, t1b, rs_in, nullptr, b1, h1, nullptr, N);

    // ---- Layer 2: 64 -> 32; z -> d_out, shadow zb = bf16(z * rs_out) ----
    k_gemm_tiled<64, 32, 64, true><<<(N + 63) / 64, B, 0, stream>>>(
        h1, W2, rs_out, nullptr, t2b, N);
    k_gather_b<32, false, true, true><<<(N + 63) / 64, B, 0, stream>>>(
        row_ptr, csr_src, t2b, rs_in, rs_out, b2, z_out, zb, N);

    // ---- Layer 3: gather pre-scaled zb, then expand 32 -> 128 ----
    k_gather_b<32, false, false, false><<<(N + 63) / 64, B, 0, stream>>>(
        row_ptr, csr_src, zb, rs_in, nullptr, nullptr, agg3, nullptr, N);
    k_gemm_tiled<32, 128, 64, false><<<(N + 63) / 64, B, 0, stream>>>(
        agg3, W3, nullptr, b3, recon, N);
}

// Round 6
// 212.670 us; speedup vs baseline: 5.7919x; 1.0492x over previous
//
#include <hip/hip_runtime.h>
#include <hip/hip_bf16.h>

// GraphAutoencoder: 3x GraphConv (DGL norm='both') on fixed graph.
// N=50000 nodes, E=600000 edges, widths 128 -> 64 -> 32 -> 128.
//
// R1: scatter-atomics RMW-bound (485us). R2: CSR+gather -> 340us.
// R3: tiled GEMM/gathers -> 277us. R4: atomic-free counting sort -> 243us.
//     (harness 0xAA poison of 256MiB ws = fixed ~43us inside timed window)
// R5: bf16 gather sources + pre-scaled zb shadow -> 223us.
// R6: row-local fusion: gather+relu+GEMM2 in one kernel (h1 never
//     materialized), gather+GEMM3 in one kernel (agg3 never materialized),
//     reduce+scan1 fused. 12 -> 9 kernels, -38.4MB HBM.
//
// Pipeline:
//   A: t1b = bf16(rs_out .* (X @ W1))                      [GEMM]
//   B: per node: agg=gather(t1b); h=relu(rs_in*agg+b1);
//      t2b = bf16(rs_out .* (h @ W2))                      [fused]
//   C: z = rs_in*gather(t2b)+b2 -> d_out; zb = bf16(z*rs_out)
//   D: recon = (rs_in .* gather(zb)) @ W3 + b3 -> d_out    [fused]

#define HNB 4          // node bins
#define HPB 64         // edge partitions
#define HBIN 12500     // nodes per bin (HNB*HBIN == N)
typedef unsigned short u16;

__device__ __forceinline__ float bfhi(unsigned u) {
    unsigned v = u & 0xFFFF0000u;
    return __builtin_bit_cast(float, v);
}
__device__ __forceinline__ float bflo(unsigned u) {
    unsigned v = u << 16;
    return __builtin_bit_cast(float, v);
}
__device__ __forceinline__ unsigned f2bf(float f) {   // f32 -> bf16 RNE
    unsigned u = __builtin_bit_cast(unsigned, f);
    return (u + 0x7FFFu + ((u >> 16) & 1u)) >> 16;
}

// ---------------- histogram: u16 slab[2][HNB][HPB][HBIN] ----------------
__global__ __launch_bounds__(256) void k_hist2(
    const int* __restrict__ src, const int* __restrict__ dst,
    u16* __restrict__ slab, int E, int slice)
{
    __shared__ int h[HBIN];
    const int which = blockIdx.x / (HNB * HPB);
    const int bin   = (blockIdx.x / HPB) % HNB;
    const int p     = blockIdx.x % HPB;
    const int* __restrict__ idx = which ? dst : src;

    for (int i = threadIdx.x; i < HBIN; i += 256) h[i] = 0;
    __syncthreads();

    const int lo  = bin * HBIN;
    const int beg = p * slice;
    const int fin = min(beg + slice, E);
    for (int i = beg + threadIdx.x * 4; i + 3 < fin; i += 1024) {
        const int4 v = *(const int4*)(idx + i);
        int u;
        u = v.x - lo; if ((unsigned)u < (unsigned)HBIN) atomicAdd(&h[u], 1);
        u = v.y - lo; if ((unsigned)u < (unsigned)HBIN) atomicAdd(&h[u], 1);
        u = v.z - lo; if ((unsigned)u < (unsigned)HBIN) atomicAdd(&h[u], 1);
        u = v.w - lo; if ((unsigned)u < (unsigned)HBIN) atomicAdd(&h[u], 1);
    }
    for (int i = beg + ((fin - beg) & ~3) + threadIdx.x; i < fin; i += 256) {
        int u = idx[i] - lo;
        if ((unsigned)u < (unsigned)HBIN) atomicAdd(&h[u], 1);
    }
    __syncthreads();

    unsigned* out = (unsigned*)(slab + (size_t)blockIdx.x * HBIN);
    for (int i = threadIdx.x; i < HBIN / 2; i += 256)
        out[i] = (unsigned)h[2 * i] | ((unsigned)h[2 * i + 1] << 16);
}

// degrees -> rsqrt; dst half -> per-partition excl offsets (in place);
// PLUS block-level inclusive scan of in-degree (fused old scan1).
__global__ __launch_bounds__(256) void k_reduce_scan(
    u16* __restrict__ slab, float* __restrict__ rs_out, float* __restrict__ rs_in,
    int* __restrict__ partial, int* __restrict__ blocksum, int N)
{
    __shared__ int tmp[256];
    const int tid = threadIdx.x;
    const int i = blockIdx.x * 256 + tid;

    int run = 0;
    if (i < N) {
        const int bin = i / HBIN;
        const int off = i - bin * HBIN;
        const u16* s_src = slab + ((size_t)(bin * HPB)) * HBIN + off;
        u16*       s_dst = slab + ((size_t)((HNB + bin) * HPB)) * HBIN + off;

        int so = 0;
#pragma unroll
        for (int p = 0; p < HPB; ++p) so += s_src[(size_t)p * HBIN];
#pragma unroll
        for (int p = 0; p < HPB; ++p) {
            const int c = s_dst[(size_t)p * HBIN];
            s_dst[(size_t)p * HBIN] = (u16)run;
            run += c;
        }
        rs_out[i] = rsqrtf(fmaxf((float)so, 1.0f));
        rs_in[i]  = rsqrtf(fmaxf((float)run, 1.0f));
    }
    tmp[tid] = run; __syncthreads();
    for (int off = 1; off < 256; off <<= 1) {
        int t = (tid >= off) ? tmp[tid - off] : 0;
        __syncthreads(); tmp[tid] += t; __syncthreads();
    }
    if (i < N) partial[i] = tmp[tid];
    if (tid == 255) blocksum[blockIdx.x] = tmp[255];
}

__global__ void k_scan2(int* __restrict__ blocksum, int nb) {  // nb<=256
    __shared__ int tmp[256];
    const int tid = threadIdx.x;
    int v = (tid < nb) ? blocksum[tid] : 0;
    tmp[tid] = v; __syncthreads();
    for (int off = 1; off < 256; off <<= 1) {
        int t = (tid >= off) ? tmp[tid - off] : 0;
        __syncthreads(); tmp[tid] += t; __syncthreads();
    }
    if (tid < nb) blocksum[tid] = tmp[tid];
}

__global__ void k_scan3(const int* __restrict__ partial, const int* __restrict__ blocksum,
                        int* __restrict__ row_ptr, int n) {
    const int i = blockIdx.x * 256 + threadIdx.x;
    if (i < n) {
        const int base = (blockIdx.x > 0) ? blocksum[blockIdx.x - 1] : 0;
        row_ptr[i + 1] = partial[i] + base;
        if (i == 0) row_ptr[0] = 0;
    }
}

// ---------- CSR fill: LDS cursors (zero global atomics) ----------
__global__ __launch_bounds__(256) void k_fill2(
    const int* __restrict__ src, const int* __restrict__ dst,
    const int* __restrict__ row_ptr, const u16* __restrict__ slab,
    int* __restrict__ csr_src, int E, int slice, int N)
{
    __shared__ int cur[HBIN];
    const int bin = blockIdx.x / HPB;
    const int p   = blockIdx.x % HPB;
    const int lo  = bin * HBIN;

    const u16* part_off = slab + ((size_t)((HNB + bin) * HPB + p)) * HBIN;
    for (int j = threadIdx.x; j < HBIN; j += 256) {
        const int node = lo + j;
        cur[j] = (node < N) ? (row_ptr[node] + (int)part_off[j]) : 0;
    }
    __syncthreads();

    const int beg = p * slice;
    const int fin = min(beg + slice, E);
    for (int i = beg + threadIdx.x * 4; i + 3 < fin; i += 1024) {
        const int4 d = *(const int4*)(dst + i);
        const int4 s = *(const int4*)(src + i);
        int u;
        u = d.x - lo; if ((unsigned)u < (unsigned)HBIN) csr_src[atomicAdd(&cur[u], 1)] = s.x;
        u = d.y - lo; if ((unsigned)u < (unsigned)HBIN) csr_src[atomicAdd(&cur[u], 1)] = s.y;
        u = d.z - lo; if ((unsigned)u < (unsigned)HBIN) csr_src[atomicAdd(&cur[u], 1)] = s.z;
        u = d.w - lo; if ((unsigned)u < (unsigned)HBIN) csr_src[atomicAdd(&cur[u], 1)] = s.w;
    }
    for (int i = beg + ((fin - beg) & ~3) + threadIdx.x; i < fin; i += 256) {
        int u = dst[i] - lo;
        if ((unsigned)u < (unsigned)HBIN) csr_src[atomicAdd(&cur[u], 1)] = src[i];
    }
}

// ---------------- GEMM A: t1b = bf16(rs_out .* (X @ W1)) ----------------
template <int IN_F, int OUT_F, int TM>
__global__ __launch_bounds__(256) void k_gemm_bf16out(
    const float* __restrict__ X, const float* __restrict__ W,
    const float* __restrict__ rowscale, u16* __restrict__ Y, int n)
{
    constexpr int CT  = OUT_F / 4;
    constexpr int RT  = 256 / CT;
    constexpr int RPT = TM / RT;
    constexpr int XS  = IN_F + 4;
    __shared__ float sW[IN_F * OUT_F];
    __shared__ float sX[TM * XS];
    const int tid = threadIdx.x;
    const int row0 = blockIdx.x * TM;

    for (int i = tid; i < IN_F * OUT_F / 4; i += 256)
        ((float4*)sW)[i] = ((const float4*)W)[i];
    for (int i = tid; i < TM * IN_F / 4; i += 256) {
        const int r  = i / (IN_F / 4);
        const int c4 = (i % (IN_F / 4)) * 4;
        const int gr = row0 + r;
        float4 v = make_float4(0.f, 0.f, 0.f, 0.f);
        if (gr < n) v = *(const float4*)(X + (long)gr * IN_F + c4);
        *(float4*)(sX + r * XS + c4) = v;
    }
    __syncthreads();

    const int tc = tid % CT;
    const int tr = tid / CT;
    float4 acc[RPT];
#pragma unroll
    for (int i = 0; i < RPT; ++i) acc[i] = make_float4(0.f, 0.f, 0.f, 0.f);

#pragma unroll 8
    for (int k = 0; k < IN_F; ++k) {
        const float4 w = *(const float4*)(sW + k * OUT_F + 4 * tc);
#pragma unroll
        for (int i = 0; i < RPT; ++i) {
            const float xv = sX[(tr + i * RT) * XS + k];
            acc[i].x += xv * w.x; acc[i].y += xv * w.y;
            acc[i].z += xv * w.z; acc[i].w += xv * w.w;
        }
    }

#pragma unroll
    for (int i = 0; i < RPT; ++i) {
        const int gr = row0 + tr + i * RT;
        if (gr < n) {
            float4 v = acc[i];
            const float s = rowscale[gr];
            v.x *= s; v.y *= s; v.z *= s; v.w *= s;
            uint2 pk;
            pk.x = f2bf(v.x) | (f2bf(v.y) << 16);
            pk.y = f2bf(v.z) | (f2bf(v.w) << 16);
            *(uint2*)(Y + (size_t)gr * OUT_F + 4 * tc) = pk;
        }
    }
}

// ---------------- fused B: gather(t1b,64) + relu-epi + @W2 -> t2b ----------------
__global__ __launch_bounds__(256) void k_gather_gemm_B(
    const int* __restrict__ row_ptr, const int* __restrict__ csr_src,
    const u16* __restrict__ t1b, const float* __restrict__ rs_in,
    const float* __restrict__ rs_out, const float* __restrict__ b1,
    const float* __restrict__ W2, u16* __restrict__ t2b, int N)
{
    __shared__ float sh[32][72];         // 32 h-rows (64 wide, padded)
    __shared__ float sW[64 * 32];        // W2: 8KB
    const int tid = threadIdx.x;

    for (int i = tid; i < 64 * 32 / 4; i += 256)
        ((float4*)sW)[i] = ((const float4*)W2)[i];

    const int nloc = tid / 8;
    const int node = blockIdx.x * 32 + nloc;
    const int c8 = (tid % 8) * 8;

    float a[8];
#pragma unroll
    for (int t = 0; t < 8; ++t) a[t] = 0.f;

    if (node < N) {
        const int beg = row_ptr[node];
        const int end = row_ptr[node + 1];
        int j = beg;
        for (; j + 3 < end; j += 4) {
            const int s0 = csr_src[j], s1 = csr_src[j + 1];
            const int s2 = csr_src[j + 2], s3 = csr_src[j + 3];
            const uint4 q0 = *(const uint4*)(t1b + (size_t)s0 * 64 + c8);
            const uint4 q1 = *(const uint4*)(t1b + (size_t)s1 * 64 + c8);
            const uint4 q2 = *(const uint4*)(t1b + (size_t)s2 * 64 + c8);
            const uint4 q3 = *(const uint4*)(t1b + (size_t)s3 * 64 + c8);
            a[0] += bflo(q0.x); a[1] += bfhi(q0.x); a[2] += bflo(q0.y); a[3] += bfhi(q0.y);
            a[4] += bflo(q0.z); a[5] += bfhi(q0.z); a[6] += bflo(q0.w); a[7] += bfhi(q0.w);
            a[0] += bflo(q1.x); a[1] += bfhi(q1.x); a[2] += bflo(q1.y); a[3] += bfhi(q1.y);
            a[4] += bflo(q1.z); a[5] += bfhi(q1.z); a[6] += bflo(q1.w); a[7] += bfhi(q1.w);
            a[0] += bflo(q2.x); a[1] += bfhi(q2.x); a[2] += bflo(q2.y); a[3] += bfhi(q2.y);
            a[4] += bflo(q2.z); a[5] += bfhi(q2.z); a[6] += bflo(q2.w); a[7] += bfhi(q2.w);
            a[0] += bflo(q3.x); a[1] += bfhi(q3.x); a[2] += bflo(q3.y); a[3] += bfhi(q3.y);
            a[4] += bflo(q3.z); a[5] += bfhi(q3.z); a[6] += bflo(q3.w); a[7] += bfhi(q3.w);
        }
        for (; j < end; ++j) {
            const int s = csr_src[j];
            const uint4 q = *(const uint4*)(t1b + (size_t)s * 64 + c8);
            a[0] += bflo(q.x); a[1] += bfhi(q.x); a[2] += bflo(q.y); a[3] += bfhi(q.y);
            a[4] += bflo(q.z); a[5] += bfhi(q.z); a[6] += bflo(q.w); a[7] += bfhi(q.w);
        }
        const float rs = rs_in[node];
#pragma unroll
        for (int t = 0; t < 8; ++t)
            a[t] = fmaxf(a[t] * rs + b1[c8 + t], 0.f);   // relu(rs_in*agg + b1)
    }
#pragma unroll
    for (int t = 0; t < 8; ++t) sh[nloc][c8 + t] = a[t];
    __syncthreads();

    // GEMM: 32 nodes x 32 cols; thread -> node=tid/8, c4=(tid%8)*4
    const int n2 = tid / 8;
    const int c4 = (tid % 8) * 4;
    float4 acc = make_float4(0.f, 0.f, 0.f, 0.f);
#pragma unroll 8
    for (int k = 0; k < 64; ++k) {
        const float xv = sh[n2][k];
        const float4 w = *(const float4*)(sW + k * 32 + c4);
        acc.x += xv * w.x; acc.y += xv * w.y; acc.z += xv * w.z; acc.w += xv * w.w;
    }
    const int gn = blockIdx.x * 32 + n2;
    if (gn < N) {
        const float s = rs_out[gn];
        uint2 pk;
        pk.x = f2bf(acc.x * s) | (f2bf(acc.y * s) << 16);
        pk.y = f2bf(acc.z * s) | (f2bf(acc.w * s) << 16);
        *(uint2*)(t2b + (size_t)gn * 32 + c4) = pk;
    }
}

// ---------------- C: gather(t2b,32) -> z (f32, d_out) + zb shadow ----------------
__global__ __launch_bounds__(256) void k_gather_C(
    const int* __restrict__ row_ptr, const int* __restrict__ csr_src,
    const u16* __restrict__ t2b, const float* __restrict__ rs_in,
    const float* __restrict__ rs_out, const float* __restrict__ b2,
    float* __restrict__ z, u16* __restrict__ zb, int N)
{
    const int node = blockIdx.x * 64 + threadIdx.x / 4;
    const int c8 = (threadIdx.x % 4) * 8;
    if (node >= N) return;

    const int beg = row_ptr[node];
    const int end = row_ptr[node + 1];
    float a[8];
#pragma unroll
    for (int t = 0; t < 8; ++t) a[t] = 0.f;

    int j = beg;
    for (; j + 3 < end; j += 4) {
        const int s0 = csr_src[j], s1 = csr_src[j + 1];
        const int s2 = csr_src[j + 2], s3 = csr_src[j + 3];
        const uint4 q0 = *(const uint4*)(t2b + (size_t)s0 * 32 + c8);
        const uint4 q1 = *(const uint4*)(t2b + (size_t)s1 * 32 + c8);
        const uint4 q2 = *(const uint4*)(t2b + (size_t)s2 * 32 + c8);
        const uint4 q3 = *(const uint4*)(t2b + (size_t)s3 * 32 + c8);
        a[0] += bflo(q0.x); a[1] += bfhi(q0.x); a[2] += bflo(q0.y); a[3] += bfhi(q0.y);
        a[4] += bflo(q0.z); a[5] += bfhi(q0.z); a[6] += bflo(q0.w); a[7] += bfhi(q0.w);
        a[0] += bflo(q1.x); a[1] += bfhi(q1.x); a[2] += bflo(q1.y); a[3] += bfhi(q1.y);
        a[4] += bflo(q1.z); a[5] += bfhi(q1.z); a[6] += bflo(q1.w); a[7] += bfhi(q1.w);
        a[0] += bflo(q2.x); a[1] += bfhi(q2.x); a[2] += bflo(q2.y); a[3] += bfhi(q2.y);
        a[4] += bflo(q2.z); a[5] += bfhi(q2.z); a[6] += bflo(q2.w); a[7] += bfhi(q2.w);
        a[0] += bflo(q3.x); a[1] += bfhi(q3.x); a[2] += bflo(q3.y); a[3] += bfhi(q3.y);
        a[4] += bflo(q3.z); a[5] += bfhi(q3.z); a[6] += bflo(q3.w); a[7] += bfhi(q3.w);
    }
    for (; j < end; ++j) {
        const int s = csr_src[j];
        const uint4 q = *(const uint4*)(t2b + (size_t)s * 32 + c8);
        a[0] += bflo(q.x); a[1] += bfhi(q.x); a[2] += bflo(q.y); a[3] += bfhi(q.y);
        a[4] += bflo(q.z); a[5] += bfhi(q.z); a[6] += bflo(q.w); a[7] += bfhi(q.w);
    }

    const float rs = rs_in[node];
    float v[8];
#pragma unroll
    for (int t = 0; t < 8; ++t) v[t] = a[t] * rs + b2[c8 + t];

    float* o = z + (size_t)node * 32 + c8;
    *(float4*)(o)     = make_float4(v[0], v[1], v[2], v[3]);
    *(float4*)(o + 4) = make_float4(v[4], v[5], v[6], v[7]);

    const float ss = rs_out[node];
    uint4 pk;
    pk.x = f2bf(v[0] * ss) | (f2bf(v[1] * ss) << 16);
    pk.y = f2bf(v[2] * ss) | (f2bf(v[3] * ss) << 16);
    pk.z = f2bf(v[4] * ss) | (f2bf(v[5] * ss) << 16);
    pk.w = f2bf(v[6] * ss) | (f2bf(v[7] * ss) << 16);
    *(uint4*)(zb + (size_t)node * 32 + c8) = pk;
}

// ---------------- fused D: gather(zb,32) + @W3 + b3 -> recon ----------------
__global__ __launch_bounds__(256) void k_gather_gemm_D(
    const int* __restrict__ row_ptr, const int* __restrict__ csr_src,
    const u16* __restrict__ zb, const float* __restrict__ rs_in,
    const float* __restrict__ W3, const float* __restrict__ b3,
    float* __restrict__ recon, int N)
{
    __shared__ float sa[64][36];         // 64 agg rows (32 wide, padded)
    __shared__ float sW[32 * 128];       // W3: 16KB
    const int tid = threadIdx.x;

    for (int i = tid; i < 32 * 128 / 4; i += 256)
        ((float4*)sW)[i] = ((const float4*)W3)[i];

    const int nloc = tid / 4;
    const int node = blockIdx.x * 64 + nloc;
    const int c8 = (tid % 4) * 8;

    float a[8];
#pragma unroll
    for (int t = 0; t < 8; ++t) a[t] = 0.f;

    if (node < N) {
        const int beg = row_ptr[node];
        const int end = row_ptr[node + 1];
        int j = beg;
        for (; j + 3 < end; j += 4) {
            const int s0 = csr_src[j], s1 = csr_src[j + 1];
            const int s2 = csr_src[j + 2], s3 = csr_src[j + 3];
            const uint4 q0 = *(const uint4*)(zb + (size_t)s0 * 32 + c8);
            const uint4 q1 = *(const uint4*)(zb + (size_t)s1 * 32 + c8);
            const uint4 q2 = *(const uint4*)(zb + (size_t)s2 * 32 + c8);
            const uint4 q3 = *(const uint4*)(zb + (size_t)s3 * 32 + c8);
            a[0] += bflo(q0.x); a[1] += bfhi(q0.x); a[2] += bflo(q0.y); a[3] += bfhi(q0.y);
            a[4] += bflo(q0.z); a[5] += bfhi(q0.z); a[6] += bflo(q0.w); a[7] += bfhi(q0.w);
            a[0] += bflo(q1.x); a[1] += bfhi(q1.x); a[2] += bflo(q1.y); a[3] += bfhi(q1.y);
            a[4] += bflo(q1.z); a[5] += bfhi(q1.z); a[6] += bflo(q1.w); a[7] += bfhi(q1.w);
            a[0] += bflo(q2.x); a[1] += bfhi(q2.x); a[2] += bflo(q2.y); a[3] += bfhi(q2.y);
            a[4] += bflo(q2.z); a[5] += bfhi(q2.z); a[6] += bflo(q2.w); a[7] += bfhi(q2.w);
            a[0] += bflo(q3.x); a[1] += bfhi(q3.x); a[2] += bflo(q3.y); a[3] += bfhi(q3.y);
            a[4] += bflo(q3.z); a[5] += bfhi(q3.z); a[6] += bflo(q3.w); a[7] += bfhi(q3.w);
        }
        for (; j < end; ++j) {
            const int s = csr_src[j];
            const uint4 q = *(const uint4*)(zb + (size_t)s * 32 + c8);
            a[0] += bflo(q.x); a[1] += bfhi(q.x); a[2] += bflo(q.y); a[3] += bfhi(q.y);
            a[4] += bflo(q.z); a[5] += bfhi(q.z); a[6] += bflo(q.w); a[7] += bfhi(q.w);
        }
        const float rs = rs_in[node];
#pragma unroll
        for (int t = 0; t < 8; ++t) a[t] *= rs;
    }
#pragma unroll
    for (int t = 0; t < 8; ++t) sa[nloc][c8 + t] = a[t];
    __syncthreads();

    // GEMM: 64 nodes x 128 cols; thread -> 8 nodes x 4 cols
    const int ng = (tid / 32) * 8;       // node group base
    const int c4 = (tid % 32) * 4;
    const float4 bb = *(const float4*)(b3 + c4);
    float4 acc[8];
#pragma unroll
    for (int i = 0; i < 8; ++i) acc[i] = bb;
#pragma unroll 4
    for (int k = 0; k < 32; ++k) {
        const float4 w = *(const float4*)(sW + k * 128 + c4);
#pragma unroll
        for (int i = 0; i < 8; ++i) {
            const float xv = sa[ng + i][k];
            acc[i].x += xv * w.x; acc[i].y += xv * w.y;
            acc[i].z += xv * w.z; acc[i].w += xv * w.w;
        }
    }
#pragma unroll
    for (int i = 0; i < 8; ++i) {
        const int gn = blockIdx.x * 64 + ng + i;
        if (gn < N) *(float4*)(recon + (size_t)gn * 128 + c4) = acc[i];
    }
}

extern "C" void kernel_launch(void* const* d_in, const int* in_sizes, int n_in,
                              void* d_out, int out_size, void* d_ws, size_t ws_size,
                              hipStream_t stream) {
    const float* feat = (const float*)d_in[0];   // [N,128]
    const int*   src  = (const int*)d_in[1];     // [E]
    const int*   dst  = (const int*)d_in[2];     // [E]
    const float* W1   = (const float*)d_in[3];   // [128,64]
    const float* b1   = (const float*)d_in[4];   // [64]
    const float* W2   = (const float*)d_in[5];   // [64,32]
    const float* b2   = (const float*)d_in[6];   // [32]
    const float* W3   = (const float*)d_in[7];   // [32,128]
    const float* b3   = (const float*)d_in[8];   // [128]

    const int E = in_sizes[1];
    const int N = in_sizes[0] / 128;             // 50000 == HNB*HBIN
    const int slice = (((E + HPB - 1) / HPB) + 3) & ~3;

    // ---- workspace layout (16B alignment at every boundary) ----
    const size_t SLABN = 2UL * HNB * HPB * HBIN;  // 6.4M u16 = 12.8MB
    u16* slab     = (u16*)d_ws;                   // dead after k_fill2
    int* row_ptr  = (int*)(slab + SLABN);         // [N+16]
    int* scan_p   = row_ptr + N + 16;             // [N]
    int* blocksum = scan_p + N;                   // [256]
    int* csr_src  = blocksum + 256;               // [E]
    float* rs_out = (float*)(csr_src + E);        // [N]
    float* rs_in  = rs_out + N;                   // [N]
    u16* t2b      = (u16*)(rs_in + N);            // [N,32] bf16
    u16* zb       = t2b + (size_t)N * 32;         // [N,32] bf16 (z * rs_out)
    u16* t1b      = (u16*)slab;                   // [N,64] bf16, aliases dead slab

    float* z_out  = (float*)d_out;                // [N,32]
    float* recon  = z_out + (size_t)N * 32;       // [N,128]

    const int B = 256;
    const int nb_scan = (N + 255) / 256;          // 196

    // ---- atomic-free graph preprocessing ----
    k_hist2<<<2 * HNB * HPB, B, 0, stream>>>(src, dst, slab, E, slice);
    k_reduce_scan<<<nb_scan, B, 0, stream>>>(slab, rs_out, rs_in, scan_p, blocksum, N);
    k_scan2<<<1, B, 0, stream>>>(blocksum, nb_scan);
    k_scan3<<<nb_scan, B, 0, stream>>>(scan_p, blocksum, row_ptr, N);
    k_fill2<<<HNB * HPB, B, 0, stream>>>(src, dst, row_ptr, slab, csr_src, E, slice, N);

    // ---- A: t1b = bf16(rs_out .* (X @ W1)) (overwrites slab after fill) ----
    k_gemm_bf16out<128, 64, 32><<<(N + 31) / 32, B, 0, stream>>>(
        feat, W1, rs_out, t1b, N);

    // ---- B: gather(t1b) + relu + @W2 -> t2b ----
    k_gather_gemm_B<<<(N + 31) / 32, B, 0, stream>>>(
        row_ptr, csr_src, t1b, rs_in, rs_out, b1, W2, t2b, N);

    // ---- C: gather(t2b) -> z (d_out) + zb shadow ----
    k_gather_C<<<(N + 63) / 64, B, 0, stream>>>(
        row_ptr, csr_src, t2b, rs_in, rs_out, b2, z_out, zb, N);

    // ---- D: gather(zb) + @W3 + b3 -> recon ----
    k_gather_gemm_D<<<(N + 63) / 64, B, 0, stream>>>(
        row_ptr, csr_src, zb, rs_in, W3, b3, recon, N);
}